// Round 1
// baseline (326.335 us; speedup 1.0000x reference)
//
#include <hip/hip_runtime.h>
#include <math.h>

#define B  128
#define T  1024
#define DM 512
#define DQ 1024
#define DA 128
#define F  32
#define KW 31

#define TT 64    // rows per block in energy kernel
#define DC 32    // d-chunk
#define TSEG 4   // t-segments for context partials

__device__ __forceinline__ float fast_tanh(float x) {
    float ax = fabsf(x);
    float e = __expf(-2.0f * ax);
    float t = 1.0f - 2.0f * e / (1.0f + e);
    return copysignf(t, x);
}

// --- pq = query @ Wq  (B x DA); CW = conv_k[:,0,:] @ Wloc (KW x DA) ---
__global__ __launch_bounds__(128) void prep_kernel(
        const float* __restrict__ query, const float* __restrict__ Wq,
        const float* __restrict__ conv_k, const float* __restrict__ Wloc,
        float* __restrict__ pq, float* __restrict__ CW) {
    int a = threadIdx.x;
    int blk = blockIdx.x;
    if (blk < B) {
        const float* q = query + blk * DQ;
        float s = 0.f;
        for (int i = 0; i < DQ; ++i) s += q[i] * Wq[i * DA + a];
        pq[blk * DA + a] = s;
    } else {
        int k = blk - B;
        float s = 0.f;
        #pragma unroll
        for (int f = 0; f < F; ++f) s += conv_k[k * F + f] * Wloc[f * DA + a];
        CW[k * DA + a] = s;
    }
}

// --- energy[b,t] = tanh(memory@Wmem + pq + loc) . v_w + v_b ---
__global__ __launch_bounds__(256) void energy_kernel(
        const float* __restrict__ memory, const float* __restrict__ Wmem,
        const float* __restrict__ state, const float* __restrict__ pq,
        const float* __restrict__ CW, const float* __restrict__ v_w,
        const float* __restrict__ v_b, float* __restrict__ energy) {
    __shared__ __align__(16) float memT[TT * DC];        // 8 KB
    __shared__ __align__(16) float wT[DC * DA];          // 16 KB
    __shared__ __align__(16) float cwT[KW * DA];         // 15.875 KB
    __shared__ __align__(16) float st[TT + KW - 1];      // 94 floats

    int b  = blockIdx.x / (T / TT);
    int t0 = (blockIdx.x % (T / TT)) * TT;
    int tid = threadIdx.x;
    int tx = tid & 31;       // column group: a = tx*4 + j
    int ty = tid >> 5;       // 0..7, rows r = ty*8 + i

    // stage CW and state segment (once)
    for (int i = tid; i < KW * DA; i += 256) cwT[i] = CW[i];
    for (int i = tid; i < TT + KW - 1; i += 256) {
        int t = t0 + i - (KW / 2);
        st[i] = (t >= 0 && t < T) ? state[b * T + t] : 0.f;
    }

    float acc[8][4];
    #pragma unroll
    for (int i = 0; i < 8; ++i)
        #pragma unroll
        for (int j = 0; j < 4; ++j) acc[i][j] = 0.f;

    const float* memB = memory + (size_t)b * T * DM + (size_t)t0 * DM;

    for (int d0 = 0; d0 < DM; d0 += DC) {
        __syncthreads();
        {   // stage memory tile: TT x DC, float4 (2 per thread)
            int row = tid >> 3;    // 0..31
            int seg = tid & 7;     // 0..7 (8 float4 per row)
            const float4* s0 = (const float4*)(memB + (size_t)row * DM + d0) + seg;
            ((float4*)memT)[row * 8 + seg] = *s0;
            const float4* s1 = (const float4*)(memB + (size_t)(row + 32) * DM + d0) + seg;
            ((float4*)memT)[(row + 32) * 8 + seg] = *s1;
        }
        {   // stage Wmem chunk: DC x DA, flat float4 (4 per thread)
            const float4* src = (const float4*)(Wmem + (size_t)d0 * DA);
            float4* dst = (float4*)wT;
            #pragma unroll
            for (int i = 0; i < 4; ++i) dst[tid + 256 * i] = src[tid + 256 * i];
        }
        __syncthreads();
        #pragma unroll
        for (int d = 0; d < DC; ++d) {
            float4 w = ((const float4*)wT)[d * 32 + tx];
            #pragma unroll
            for (int i = 0; i < 8; ++i) {
                float m = memT[(ty * 8 + i) * DC + d];
                acc[i][0] += m * w.x;
                acc[i][1] += m * w.y;
                acc[i][2] += m * w.z;
                acc[i][3] += m * w.w;
            }
        }
    }

    float4 pqv = ((const float4*)(pq + b * DA))[tx];
    float4 vwv = ((const float4*)v_w)[tx];
    float vb = *v_b;

    #pragma unroll
    for (int i = 0; i < 8; ++i) {
        int r = ty * 8 + i;
        float4 loc = make_float4(0.f, 0.f, 0.f, 0.f);
        #pragma unroll
        for (int k = 0; k < KW; ++k) {
            float s = st[r + k];
            float4 cw = ((const float4*)cwT)[k * 32 + tx];
            loc.x += s * cw.x; loc.y += s * cw.y;
            loc.z += s * cw.z; loc.w += s * cw.w;
        }
        float e = fast_tanh(acc[i][0] + pqv.x + loc.x) * vwv.x
                + fast_tanh(acc[i][1] + pqv.y + loc.y) * vwv.y
                + fast_tanh(acc[i][2] + pqv.z + loc.z) * vwv.z
                + fast_tanh(acc[i][3] + pqv.w + loc.w) * vwv.w;
        #pragma unroll
        for (int off = 16; off > 0; off >>= 1) e += __shfl_xor(e, off, 64);
        if (tx == 0) energy[b * T + t0 + r] = e + vb;
    }
}

// --- softmax over T, alignments & new_state ---
__global__ __launch_bounds__(256) void softmax_kernel(
        const float* __restrict__ energy, const float* __restrict__ state,
        float* __restrict__ alignments, float* __restrict__ new_state) {
    int b = blockIdx.x;
    int tid = threadIdx.x;         // 256 threads, 4 energies each
    __shared__ float rmax[4], rsum[4];
    float4 ev = ((const float4*)(energy + b * T))[tid];
    float m = fmaxf(fmaxf(ev.x, ev.y), fmaxf(ev.z, ev.w));
    #pragma unroll
    for (int off = 32; off > 0; off >>= 1) m = fmaxf(m, __shfl_xor(m, off, 64));
    if ((tid & 63) == 0) rmax[tid >> 6] = m;
    __syncthreads();
    m = fmaxf(fmaxf(rmax[0], rmax[1]), fmaxf(rmax[2], rmax[3]));
    float4 x;
    x.x = __expf(ev.x - m); x.y = __expf(ev.y - m);
    x.z = __expf(ev.z - m); x.w = __expf(ev.w - m);
    float s = x.x + x.y + x.z + x.w;
    #pragma unroll
    for (int off = 32; off > 0; off >>= 1) s += __shfl_xor(s, off, 64);
    if ((tid & 63) == 0) rsum[tid >> 6] = s;
    __syncthreads();
    s = rsum[0] + rsum[1] + rsum[2] + rsum[3];
    float inv = 1.0f / s;
    float4 st4 = ((const float4*)(state + b * T))[tid];
    float4 al = make_float4(x.x * inv, x.y * inv, x.z * inv, x.w * inv);
    ((float4*)(alignments + b * T))[tid] = al;
    float4 ns = make_float4(al.x + st4.x, al.y + st4.y, al.z + st4.z, al.w + st4.w);
    ((float4*)(new_state + b * T))[tid] = ns;
}

// --- context partials: partial[seg][b][d] = sum_{t in seg} align * memory ---
__global__ __launch_bounds__(256) void context_partial_kernel(
        const float* __restrict__ memory, const float* __restrict__ alignments,
        float* __restrict__ partial) {
    int b = blockIdx.x;
    int seg = blockIdx.y;
    int tid = threadIdx.x;       // 256 threads, d = tid and tid+256
    __shared__ float al[T / TSEG];
    int t0 = seg * (T / TSEG);
    al[tid] = alignments[b * T + t0 + tid];
    __syncthreads();
    const float* memB = memory + (size_t)b * T * DM + (size_t)t0 * DM;
    float acc0 = 0.f, acc1 = 0.f;
    #pragma unroll 4
    for (int t = 0; t < T / TSEG; ++t) {
        float a = al[t];
        acc0 += a * memB[(size_t)t * DM + tid];
        acc1 += a * memB[(size_t)t * DM + tid + 256];
    }
    partial[((size_t)seg * B + b) * DM + tid] = acc0;
    partial[((size_t)seg * B + b) * DM + tid + 256] = acc1;
}

__global__ __launch_bounds__(256) void context_reduce_kernel(
        const float* __restrict__ partial, float* __restrict__ context) {
    int b = blockIdx.x;
    int tid = threadIdx.x;
    #pragma unroll
    for (int j = 0; j < 2; ++j) {
        int d = tid + j * 256;
        float s = 0.f;
        #pragma unroll
        for (int g = 0; g < TSEG; ++g) s += partial[((size_t)g * B + b) * DM + d];
        context[b * DM + d] = s;
    }
}

extern "C" void kernel_launch(void* const* d_in, const int* in_sizes, int n_in,
                              void* d_out, int out_size, void* d_ws, size_t ws_size,
                              hipStream_t stream) {
    const float* query  = (const float*)d_in[0];
    const float* state  = (const float*)d_in[1];
    // d_in[2]: prev_max_alignments (unused by reference math)
    const float* memory = (const float*)d_in[3];
    const float* Wq     = (const float*)d_in[4];
    const float* Wmem   = (const float*)d_in[5];
    const float* conv_k = (const float*)d_in[6];
    const float* Wloc   = (const float*)d_in[7];
    const float* v_w    = (const float*)d_in[8];
    const float* v_b    = (const float*)d_in[9];

    float* out        = (float*)d_out;
    float* context    = out;                    // B*DM
    float* alignments = out + B * DM;           // B*T
    float* new_state  = out + B * DM + B * T;   // B*T

    char* ws = (char*)d_ws;
    float* pq      = (float*)ws;                           // 64 KB
    float* CW      = (float*)(ws + 65536);                 // 15.875 KB
    float* energy  = (float*)(ws + 81920);                 // 512 KB
    float* partial = (float*)(ws + 81920 + 524288);        // 1 MB

    prep_kernel<<<dim3(B + KW), 128, 0, stream>>>(query, Wq, conv_k, Wloc, pq, CW);
    energy_kernel<<<dim3(B * (T / TT)), 256, 0, stream>>>(memory, Wmem, state, pq, CW, v_w, v_b, energy);
    softmax_kernel<<<dim3(B), 256, 0, stream>>>(energy, state, alignments, new_state);
    context_partial_kernel<<<dim3(B, TSEG), 256, 0, stream>>>(memory, alignments, partial);
    context_reduce_kernel<<<dim3(B), 256, 0, stream>>>(partial, context);
}

// Round 2
// 144.097 us; speedup vs baseline: 2.2647x; 2.2647x over previous
//
#include <hip/hip_runtime.h>
#include <math.h>

#define B  128
#define T  1024
#define DM 512
#define DQ 1024
#define DA 128
#define F  32
#define KW 31
#define TSEG 4

typedef short s16x8 __attribute__((ext_vector_type(8)));
typedef float f32x4 __attribute__((ext_vector_type(4)));
typedef unsigned int u32;
typedef __attribute__((address_space(1))) const unsigned int gu32;
typedef __attribute__((address_space(3))) unsigned int lu32;

__device__ __forceinline__ unsigned short f2bf(float f) {
    u32 u = __builtin_bit_cast(u32, f);
    u32 r = u + 0x7FFFu + ((u >> 16) & 1u);
    return (unsigned short)(r >> 16);
}
__device__ __forceinline__ float bf2f(unsigned short h) {
    u32 u = ((u32)h) << 16;
    return __builtin_bit_cast(float, u);
}
__device__ __forceinline__ float fast_tanh(float x) {
    float ax = fabsf(x);
    float e = __expf(-2.0f * ax);
    float t = 1.0f - 2.0f * e / (1.0f + e);
    return copysignf(t, x);
}

// ---------------- prep: pq, Wmem hi/lo split (transposed+swizzled), CWt ----------------
__global__ __launch_bounds__(128) void prep_kernel(
        const float* __restrict__ query, const float* __restrict__ Wq,
        const float* __restrict__ Wmem, const float* __restrict__ conv_k,
        const float* __restrict__ Wloc,
        float* __restrict__ pq, unsigned short* __restrict__ wsplit,
        unsigned short* __restrict__ CWt) {
    int a = threadIdx.x;
    int blk = blockIdx.x;
    if (blk < B) {
        const float* q = query + blk * DQ;
        float s = 0.f;
        for (int i = 0; i < DQ; ++i) s += q[i] * Wq[i * DA + a];
        pq[blk * DA + a] = s;
    } else if (blk < B + DM) {
        int k = blk - B;
        float w0 = Wmem[k * DA + a];
        unsigned short hi = f2bf(w0);
        float d = w0 - bf2f(hi);
        unsigned short lo = f2bf(d);
        int c = k >> 6;
        int es = (k & 63) ^ ((a & 7) << 3);           // pre-swizzled for LDS reads
        int base = c * 16384 + a * 64 + es;           // [chunk][hi 8192 | lo 8192]
        wsplit[base] = hi;
        wsplit[base + 8192] = lo;
    } else {
        int k = blk - (B + DM);                       // 0..31 (row 31 = zero pad)
        float s = 0.f;
        if (k < KW) {
            #pragma unroll
            for (int f = 0; f < F; ++f) s += conv_k[k * F + f] * Wloc[f * DA + a];
        }
        CWt[a * 32 + k] = f2bf(s);                    // [a][k] contiguous
    }
}

// ---------------- energy via bf16 MFMA (3-term split) + fused loc conv ----------------
__global__ __launch_bounds__(256, 3) void energy_mfma(
        const float* __restrict__ memory, const float* __restrict__ state,
        const float* __restrict__ pq, const unsigned short* __restrict__ wsplit,
        const unsigned short* __restrict__ CWt, const float* __restrict__ v_w,
        const float* __restrict__ v_b, float* __restrict__ energy) {
    __shared__ unsigned short Wlds[16384];   // 32 KB: hi [0,8192) elems, lo [8192,16384)
    __shared__ float stl[160];
    __shared__ float pql[DA];
    __shared__ float vwl[DA];

    int tid = threadIdx.x;
    int w = tid >> 6, l = tid & 63, r = l & 15, g = l >> 4;
    int b  = blockIdx.x >> 3;
    int t0 = (blockIdx.x & 7) << 7;          // 128-row tile

    for (int i = tid; i < 160; i += 256) {
        int t = t0 - 15 + i;
        stl[i] = (i < 159 && t >= 0 && t < T) ? state[b * T + t] : 0.f;
    }
    if (tid < DA) { pql[tid] = pq[b * DA + tid]; vwl[tid] = v_w[tid]; }

    f32x4 acc0[8], acc1[8];
    #pragma unroll
    for (int nt = 0; nt < 8; ++nt) {
        acc0[nt] = (f32x4){0.f, 0.f, 0.f, 0.f};
        acc1[nt] = (f32x4){0.f, 0.f, 0.f, 0.f};
    }

    const int swz8 = (r & 7) << 3;
    const size_t arow = ((size_t)(b * T + t0 + w * 32 + r)) * DM;

    for (int c = 0; c < 8; ++c) {
        __syncthreads();                      // previous chunk's ds_reads complete
        {
            const unsigned short* src = wsplit + (size_t)c * 16384 + tid * 8;
            #pragma unroll
            for (int rd = 0; rd < 8; ++rd)
                __builtin_amdgcn_global_load_lds((gu32*)(src + rd * 2048),
                                                 (lu32*)(Wlds + (w << 9) + rd * 2048),
                                                 16, 0, 0);
        }
        __syncthreads();                      // staged (vmcnt drained by barrier)

        const float* Ab = memory + arow + c * 64;
        #pragma unroll
        for (int kk = 0; kk < 2; ++kk) {
            const float* p0 = Ab + kk * 32 + g * 8;
            f32x4 f00 = *(const f32x4*)p0;
            f32x4 f01 = *(const f32x4*)(p0 + 4);
            const float* p1 = p0 + 16 * DM;
            f32x4 f10 = *(const f32x4*)p1;
            f32x4 f11 = *(const f32x4*)(p1 + 4);
            s16x8 Ah0, Al0, Ah1, Al1;
            #pragma unroll
            for (int j = 0; j < 4; ++j) {
                unsigned short h;
                h = f2bf(f00[j]); Ah0[j]     = (short)h; Al0[j]     = (short)f2bf(f00[j] - bf2f(h));
                h = f2bf(f01[j]); Ah0[4 + j] = (short)h; Al0[4 + j] = (short)f2bf(f01[j] - bf2f(h));
                h = f2bf(f10[j]); Ah1[j]     = (short)h; Al1[j]     = (short)f2bf(f10[j] - bf2f(h));
                h = f2bf(f11[j]); Ah1[4 + j] = (short)h; Al1[4 + j] = (short)f2bf(f11[j] - bf2f(h));
            }
            int off = (kk * 32 + g * 8) ^ swz8;
            #pragma unroll
            for (int nt = 0; nt < 8; ++nt) {
                const unsigned short* bp = Wlds + (nt * 16 + r) * 64 + off;
                s16x8 Bh = *(const s16x8*)bp;
                s16x8 Bl = *(const s16x8*)(bp + 8192);
                acc0[nt] = __builtin_amdgcn_mfma_f32_16x16x32_bf16(Ah0, Bh, acc0[nt], 0, 0, 0);
                acc0[nt] = __builtin_amdgcn_mfma_f32_16x16x32_bf16(Ah0, Bl, acc0[nt], 0, 0, 0);
                acc0[nt] = __builtin_amdgcn_mfma_f32_16x16x32_bf16(Al0, Bh, acc0[nt], 0, 0, 0);
                acc1[nt] = __builtin_amdgcn_mfma_f32_16x16x32_bf16(Ah1, Bh, acc1[nt], 0, 0, 0);
                acc1[nt] = __builtin_amdgcn_mfma_f32_16x16x32_bf16(Ah1, Bl, acc1[nt], 0, 0, 0);
                acc1[nt] = __builtin_amdgcn_mfma_f32_16x16x32_bf16(Al1, Bh, acc1[nt], 0, 0, 0);
            }
        }
    }

    // ---- stage CWt (8 KB) into freed LDS, fold loc conv into the accumulators ----
    __syncthreads();
    #pragma unroll
    for (int rd = 0; rd < 2; ++rd)
        __builtin_amdgcn_global_load_lds((gu32*)(CWt + rd * 2048 + tid * 8),
                                         (lu32*)(Wlds + (w << 9) + rd * 2048),
                                         16, 0, 0);
    __syncthreads();

    s16x8 st0, st1;
    {
        int base0 = w * 32 + r + g * 8;
        #pragma unroll
        for (int j = 0; j < 8; ++j) {
            st0[j] = (short)f2bf(stl[base0 + j]);
            st1[j] = (short)f2bf(stl[base0 + 16 + j]);
        }
    }
    #pragma unroll
    for (int nt = 0; nt < 8; ++nt) {
        const unsigned short* cp = Wlds + (nt * 16 + r) * 32 + g * 8;
        s16x8 cw = *(const s16x8*)cp;
        acc0[nt] = __builtin_amdgcn_mfma_f32_16x16x32_bf16(st0, cw, acc0[nt], 0, 0, 0);
        acc1[nt] = __builtin_amdgcn_mfma_f32_16x16x32_bf16(st1, cw, acc1[nt], 0, 0, 0);
    }

    // ---- epilogue: +pq, tanh, .v_w, 16-lane reduce, write energy ----
    float vb = *v_b;
    #pragma unroll
    for (int sub = 0; sub < 2; ++sub) {
        #pragma unroll
        for (int reg = 0; reg < 4; ++reg) {
            float p = 0.f;
            #pragma unroll
            for (int nt = 0; nt < 8; ++nt) {
                int col = nt * 16 + r;
                float v = (sub == 0) ? acc0[nt][reg] : acc1[nt][reg];
                p += fast_tanh(v + pql[col]) * vwl[col];
            }
            p += __shfl_xor(p, 1, 16);
            p += __shfl_xor(p, 2, 16);
            p += __shfl_xor(p, 4, 16);
            p += __shfl_xor(p, 8, 16);
            if (r == 0)
                energy[b * T + t0 + w * 32 + sub * 16 + g * 4 + reg] = p + vb;
        }
    }
}

// ---------------- softmax over T, alignments & new_state ----------------
__global__ __launch_bounds__(256) void softmax_kernel(
        const float* __restrict__ energy, const float* __restrict__ state,
        float* __restrict__ alignments, float* __restrict__ new_state) {
    int b = blockIdx.x;
    int tid = threadIdx.x;
    __shared__ float rmax[4], rsum[4];
    float4 ev = ((const float4*)(energy + b * T))[tid];
    float m = fmaxf(fmaxf(ev.x, ev.y), fmaxf(ev.z, ev.w));
    #pragma unroll
    for (int off = 32; off > 0; off >>= 1) m = fmaxf(m, __shfl_xor(m, off, 64));
    if ((tid & 63) == 0) rmax[tid >> 6] = m;
    __syncthreads();
    m = fmaxf(fmaxf(rmax[0], rmax[1]), fmaxf(rmax[2], rmax[3]));
    float4 x;
    x.x = __expf(ev.x - m); x.y = __expf(ev.y - m);
    x.z = __expf(ev.z - m); x.w = __expf(ev.w - m);
    float s = x.x + x.y + x.z + x.w;
    #pragma unroll
    for (int off = 32; off > 0; off >>= 1) s += __shfl_xor(s, off, 64);
    if ((tid & 63) == 0) rsum[tid >> 6] = s;
    __syncthreads();
    s = rsum[0] + rsum[1] + rsum[2] + rsum[3];
    float inv = 1.0f / s;
    float4 st4 = ((const float4*)(state + b * T))[tid];
    float4 al = make_float4(x.x * inv, x.y * inv, x.z * inv, x.w * inv);
    ((float4*)(alignments + b * T))[tid] = al;
    float4 ns = make_float4(al.x + st4.x, al.y + st4.y, al.z + st4.z, al.w + st4.w);
    ((float4*)(new_state + b * T))[tid] = ns;
}

// ---------------- context = einsum("bt,btd->bd") ----------------
__global__ __launch_bounds__(256) void context_partial_kernel(
        const float* __restrict__ memory, const float* __restrict__ alignments,
        float* __restrict__ partial) {
    int b = blockIdx.x;
    int seg = blockIdx.y;
    int tid = threadIdx.x;
    __shared__ float al[T / TSEG];
    int t0 = seg * (T / TSEG);
    al[tid] = alignments[b * T + t0 + tid];
    __syncthreads();
    const float* memB = memory + (size_t)b * T * DM + (size_t)t0 * DM;
    float acc0 = 0.f, acc1 = 0.f;
    #pragma unroll 4
    for (int t = 0; t < T / TSEG; ++t) {
        float a = al[t];
        acc0 += a * memB[(size_t)t * DM + tid];
        acc1 += a * memB[(size_t)t * DM + tid + 256];
    }
    partial[((size_t)seg * B + b) * DM + tid] = acc0;
    partial[((size_t)seg * B + b) * DM + tid + 256] = acc1;
}

__global__ __launch_bounds__(256) void context_reduce_kernel(
        const float* __restrict__ partial, float* __restrict__ context) {
    int b = blockIdx.x;
    int tid = threadIdx.x;
    #pragma unroll
    for (int j = 0; j < 2; ++j) {
        int d = tid + j * 256;
        float s = 0.f;
        #pragma unroll
        for (int g = 0; g < TSEG; ++g) s += partial[((size_t)g * B + b) * DM + d];
        context[b * DM + d] = s;
    }
}

extern "C" void kernel_launch(void* const* d_in, const int* in_sizes, int n_in,
                              void* d_out, int out_size, void* d_ws, size_t ws_size,
                              hipStream_t stream) {
    const float* query  = (const float*)d_in[0];
    const float* state  = (const float*)d_in[1];
    const float* memory = (const float*)d_in[3];
    const float* Wq     = (const float*)d_in[4];
    const float* Wmem   = (const float*)d_in[5];
    const float* conv_k = (const float*)d_in[6];
    const float* Wloc   = (const float*)d_in[7];
    const float* v_w    = (const float*)d_in[8];
    const float* v_b    = (const float*)d_in[9];

    float* out        = (float*)d_out;
    float* context    = out;
    float* alignments = out + B * DM;
    float* new_state  = out + B * DM + B * T;

    char* ws = (char*)d_ws;
    float*          pq      = (float*)ws;                       // 64 KB
    unsigned short* wsplit  = (unsigned short*)(ws + 65536);    // 256 KB
    unsigned short* CWt     = (unsigned short*)(ws + 327680);   // 8 KB
    float*          energy  = (float*)(ws + 335872);            // 512 KB
    float*          partial = (float*)(ws + 860160);            // 1 MB

    prep_kernel<<<dim3(B + DM + 32), 128, 0, stream>>>(query, Wq, Wmem, conv_k, Wloc, pq, wsplit, CWt);
    energy_mfma<<<dim3(B * (T / 128)), 256, 0, stream>>>(memory, state, pq, wsplit, CWt, v_w, v_b, energy);
    softmax_kernel<<<dim3(B), 256, 0, stream>>>(energy, state, alignments, new_state);
    context_partial_kernel<<<dim3(B, TSEG), 256, 0, stream>>>(memory, alignments, partial);
    context_reduce_kernel<<<dim3(B), 256, 0, stream>>>(partial, context);
}

// Round 4
// 134.960 us; speedup vs baseline: 2.4180x; 1.0677x over previous
//
#include <hip/hip_runtime.h>
#include <math.h>

#define B  128
#define T  1024
#define DM 512
#define DQ 1024
#define DA 128
#define F  32
#define KW 31
#define TSEG 4

typedef short s16x8 __attribute__((ext_vector_type(8)));
typedef float f32x4 __attribute__((ext_vector_type(4)));
typedef unsigned int u32;
typedef __attribute__((address_space(1))) const unsigned int gu32;
typedef __attribute__((address_space(3))) unsigned int lu32;

__device__ __forceinline__ unsigned short f2bf(float f) {   // RNE
    u32 u = __builtin_bit_cast(u32, f);
    u32 r = u + 0x7FFFu + ((u >> 16) & 1u);
    return (unsigned short)(r >> 16);
}
__device__ __forceinline__ float bf2f(unsigned short h) {
    u32 u = ((u32)h) << 16;
    return __builtin_bit_cast(float, u);
}
__device__ __forceinline__ float fast_tanh(float x) {
    float ax = fabsf(x);
    float e = __expf(-2.0f * ax);
    float t = 1.0f - 2.0f * e / (1.0f + e);
    return copysignf(t, x);
}

// ---------------- prep: pq partials (4-way DQ split), Wmem hi/lo split, CWt ----------------
__global__ __launch_bounds__(128) void prep_kernel(
        const float* __restrict__ query, const float* __restrict__ Wq,
        const float* __restrict__ Wmem, const float* __restrict__ conv_k,
        const float* __restrict__ Wloc,
        float* __restrict__ pqp, unsigned short* __restrict__ wsplit,
        unsigned short* __restrict__ CWt) {
    int a = threadIdx.x;
    int blk = blockIdx.x;
    if (blk < 4 * B) {
        int b = blk >> 2, q = blk & 3;
        const float* qp = query + b * DQ + q * 256;
        const float* wp = Wq + (size_t)(q * 256) * DA + a;
        float s = 0.f;
        #pragma unroll 4
        for (int i = 0; i < 256; ++i) s += qp[i] * wp[(size_t)i * DA];
        pqp[(q * B + b) * DA + a] = s;
    } else if (blk < 4 * B + DM) {
        int k = blk - 4 * B;
        float w0 = Wmem[k * DA + a];
        unsigned short hi = f2bf(w0);
        float d = w0 - bf2f(hi);
        unsigned short lo = f2bf(d);
        int c = k >> 6;
        int es = (k & 63) ^ ((a & 7) << 3);           // pre-swizzled for LDS reads
        int base = c * 16384 + a * 64 + es;           // [chunk][hi 8192 | lo 8192]
        wsplit[base] = hi;
        wsplit[base + 8192] = lo;
    } else {
        int k = blk - (4 * B + DM);                   // 0..31 (row 31 = zero pad)
        float s = 0.f;
        if (k < KW) {
            #pragma unroll
            for (int f = 0; f < F; ++f) s += conv_k[k * F + f] * Wloc[f * DA + a];
        }
        CWt[a * 32 + k] = f2bf(s);                    // [a][k] contiguous
    }
}

// ---------------- energy via bf16 MFMA (3-term split) + fused loc conv ----------------
// R2-proven core: single 32 KB LDS buffer, stage-barrier-compute per chunk.
__global__ __launch_bounds__(256, 3) void energy_mfma(
        const float* __restrict__ memory, const float* __restrict__ state,
        const float* __restrict__ pqp, const unsigned short* __restrict__ wsplit,
        const unsigned short* __restrict__ CWt, const float* __restrict__ v_w,
        const float* __restrict__ v_b, float* __restrict__ energy) {
    __shared__ unsigned short Wlds[16384];   // 32 KB: hi [0,8192) elems, lo [8192,16384)
    __shared__ float stl[160];
    __shared__ float pql[DA];
    __shared__ float vwl[DA];

    int tid = threadIdx.x;
    int w = tid >> 6, l = tid & 63, r = l & 15, g = l >> 4;
    int b  = blockIdx.x >> 3;
    int t0 = (blockIdx.x & 7) << 7;          // 128-row tile

    for (int i = tid; i < 160; i += 256) {
        int t = t0 - 15 + i;
        stl[i] = (i < 159 && t >= 0 && t < T) ? state[b * T + t] : 0.f;
    }
    if (tid < DA) {
        float s = 0.f;
        #pragma unroll
        for (int q = 0; q < 4; ++q) s += pqp[(q * B + b) * DA + tid];
        pql[tid] = s;
        vwl[tid] = v_w[tid];
    }

    f32x4 acc0[8], acc1[8];
    #pragma unroll
    for (int nt = 0; nt < 8; ++nt) {
        acc0[nt] = (f32x4){0.f, 0.f, 0.f, 0.f};
        acc1[nt] = (f32x4){0.f, 0.f, 0.f, 0.f};
    }

    const int swz8 = (r & 7) << 3;
    const size_t arow = ((size_t)(b * T + t0 + w * 32 + r)) * DM;

    for (int c = 0; c < 8; ++c) {
        __syncthreads();                      // previous chunk's ds_reads complete
        {
            const unsigned short* src = wsplit + (size_t)c * 16384 + tid * 8;
            #pragma unroll
            for (int rd = 0; rd < 8; ++rd)
                __builtin_amdgcn_global_load_lds((gu32*)(src + rd * 2048),
                                                 (lu32*)(Wlds + (w << 9) + rd * 2048),
                                                 16, 0, 0);
        }
        __syncthreads();                      // staged (vmcnt drained by barrier)

        const float* Ab = memory + arow + c * 64;
        #pragma unroll
        for (int kk = 0; kk < 2; ++kk) {
            const float* p0 = Ab + kk * 32 + g * 8;
            f32x4 f00 = *(const f32x4*)p0;
            f32x4 f01 = *(const f32x4*)(p0 + 4);
            const float* p1 = p0 + 16 * DM;
            f32x4 f10 = *(const f32x4*)p1;
            f32x4 f11 = *(const f32x4*)(p1 + 4);
            s16x8 Ah0, Al0, Ah1, Al1;
            #pragma unroll
            for (int j = 0; j < 4; ++j) {
                unsigned short h;
                h = f2bf(f00[j]); Ah0[j]     = (short)h; Al0[j]     = (short)f2bf(f00[j] - bf2f(h));
                h = f2bf(f01[j]); Ah0[4 + j] = (short)h; Al0[4 + j] = (short)f2bf(f01[j] - bf2f(h));
                h = f2bf(f10[j]); Ah1[j]     = (short)h; Al1[j]     = (short)f2bf(f10[j] - bf2f(h));
                h = f2bf(f11[j]); Ah1[4 + j] = (short)h; Al1[4 + j] = (short)f2bf(f11[j] - bf2f(h));
            }
            int off = (kk * 32 + g * 8) ^ swz8;
            #pragma unroll
            for (int nt = 0; nt < 8; ++nt) {
                const unsigned short* bp = Wlds + (nt * 16 + r) * 64 + off;
                s16x8 Bh = *(const s16x8*)bp;
                s16x8 Bl = *(const s16x8*)(bp + 8192);
                acc0[nt] = __builtin_amdgcn_mfma_f32_16x16x32_bf16(Ah0, Bh, acc0[nt], 0, 0, 0);
                acc0[nt] = __builtin_amdgcn_mfma_f32_16x16x32_bf16(Ah0, Bl, acc0[nt], 0, 0, 0);
                acc0[nt] = __builtin_amdgcn_mfma_f32_16x16x32_bf16(Al0, Bh, acc0[nt], 0, 0, 0);
                acc1[nt] = __builtin_amdgcn_mfma_f32_16x16x32_bf16(Ah1, Bh, acc1[nt], 0, 0, 0);
                acc1[nt] = __builtin_amdgcn_mfma_f32_16x16x32_bf16(Ah1, Bl, acc1[nt], 0, 0, 0);
                acc1[nt] = __builtin_amdgcn_mfma_f32_16x16x32_bf16(Al1, Bh, acc1[nt], 0, 0, 0);
            }
        }
    }

    // ---- stage CWt (8 KB) into freed LDS, fold loc conv into the accumulators ----
    __syncthreads();
    #pragma unroll
    for (int rd = 0; rd < 2; ++rd)
        __builtin_amdgcn_global_load_lds((gu32*)(CWt + rd * 2048 + tid * 8),
                                         (lu32*)(Wlds + (w << 9) + rd * 2048),
                                         16, 0, 0);
    __syncthreads();

    s16x8 st0, st1;
    {
        int base0 = w * 32 + r + g * 8;
        #pragma unroll
        for (int j = 0; j < 8; ++j) {
            st0[j] = (short)f2bf(stl[base0 + j]);
            st1[j] = (short)f2bf(stl[base0 + 16 + j]);
        }
    }
    #pragma unroll
    for (int nt = 0; nt < 8; ++nt) {
        const unsigned short* cp = Wlds + (nt * 16 + r) * 32 + g * 8;
        s16x8 cw = *(const s16x8*)cp;
        acc0[nt] = __builtin_amdgcn_mfma_f32_16x16x32_bf16(st0, cw, acc0[nt], 0, 0, 0);
        acc1[nt] = __builtin_amdgcn_mfma_f32_16x16x32_bf16(st1, cw, acc1[nt], 0, 0, 0);
    }

    // ---- epilogue: +pq, tanh, .v_w, 16-lane reduce, write energy ----
    float vb = *v_b;
    #pragma unroll
    for (int sub = 0; sub < 2; ++sub) {
        #pragma unroll
        for (int reg = 0; reg < 4; ++reg) {
            float p = 0.f;
            #pragma unroll
            for (int nt = 0; nt < 8; ++nt) {
                int col = nt * 16 + r;
                float v = (sub == 0) ? acc0[nt][reg] : acc1[nt][reg];
                p += fast_tanh(v + pql[col]) * vwl[col];
            }
            p += __shfl_xor(p, 1, 16);
            p += __shfl_xor(p, 2, 16);
            p += __shfl_xor(p, 4, 16);
            p += __shfl_xor(p, 8, 16);
            if (r == 0)
                energy[b * T + t0 + w * 32 + sub * 16 + g * 4 + reg] = p + vb;
        }
    }
}

// ---------------- fused softmax + context partials ----------------
__global__ __launch_bounds__(256) void softmax_context_kernel(
        const float* __restrict__ energy, const float* __restrict__ state,
        const float* __restrict__ memory,
        float* __restrict__ alignments, float* __restrict__ new_state,
        float* __restrict__ partial) {
    int b = blockIdx.x, seg = blockIdx.y, tid = threadIdx.x;
    __shared__ float rmax[4], rsum[4];
    __shared__ float al[T / TSEG];
    __shared__ f32x4 comb[128];

    f32x4 ev = ((const f32x4*)(energy + b * T))[tid];
    float m = fmaxf(fmaxf(ev[0], ev[1]), fmaxf(ev[2], ev[3]));
    #pragma unroll
    for (int off = 32; off > 0; off >>= 1) m = fmaxf(m, __shfl_xor(m, off, 64));
    if ((tid & 63) == 0) rmax[tid >> 6] = m;
    __syncthreads();
    m = fmaxf(fmaxf(rmax[0], rmax[1]), fmaxf(rmax[2], rmax[3]));
    f32x4 x;
    x[0] = __expf(ev[0] - m); x[1] = __expf(ev[1] - m);
    x[2] = __expf(ev[2] - m); x[3] = __expf(ev[3] - m);
    float s = x[0] + x[1] + x[2] + x[3];
    #pragma unroll
    for (int off = 32; off > 0; off >>= 1) s += __shfl_xor(s, off, 64);
    if ((tid & 63) == 0) rsum[tid >> 6] = s;
    __syncthreads();
    s = rsum[0] + rsum[1] + rsum[2] + rsum[3];
    float inv = 1.0f / s;
    f32x4 a4 = x * inv;
    if ((tid >> 6) == seg) {                      // own this seg's slice
        ((f32x4*)al)[tid & 63] = a4;
        ((f32x4*)(alignments + b * T))[tid] = a4;
        f32x4 st4 = ((const f32x4*)(state + b * T))[tid];
        ((f32x4*)(new_state + b * T))[tid] = a4 + st4;
    }
    __syncthreads();

    int half = tid >> 7;
    int dg = tid & 127;
    const float* memB = memory + ((size_t)b * T + seg * (T / TSEG)) * DM;
    f32x4 acc = (f32x4){0.f, 0.f, 0.f, 0.f};
    #pragma unroll 4
    for (int it = 0; it < 128; ++it) {
        int t = it * 2 + half;
        float a = al[t];
        f32x4 v = *(const f32x4*)(memB + (size_t)t * DM + dg * 4);
        acc += v * a;
    }
    if (half) comb[dg] = acc;
    __syncthreads();
    if (!half) {
        acc += comb[dg];
        ((f32x4*)(partial + ((size_t)seg * B + b) * DM))[dg] = acc;
    }
}

__global__ __launch_bounds__(256) void context_reduce_kernel(
        const float* __restrict__ partial, float* __restrict__ context) {
    int b = blockIdx.x;
    int tid = threadIdx.x;
    #pragma unroll
    for (int j = 0; j < 2; ++j) {
        int d = tid + j * 256;
        float s = 0.f;
        #pragma unroll
        for (int g = 0; g < TSEG; ++g) s += partial[((size_t)g * B + b) * DM + d];
        context[b * DM + d] = s;
    }
}

extern "C" void kernel_launch(void* const* d_in, const int* in_sizes, int n_in,
                              void* d_out, int out_size, void* d_ws, size_t ws_size,
                              hipStream_t stream) {
    const float* query  = (const float*)d_in[0];
    const float* state  = (const float*)d_in[1];
    const float* memory = (const float*)d_in[3];
    const float* Wq     = (const float*)d_in[4];
    const float* Wmem   = (const float*)d_in[5];
    const float* conv_k = (const float*)d_in[6];
    const float* Wloc   = (const float*)d_in[7];
    const float* v_w    = (const float*)d_in[8];
    const float* v_b    = (const float*)d_in[9];

    float* out        = (float*)d_out;
    float* context    = out;
    float* alignments = out + B * DM;
    float* new_state  = out + B * DM + B * T;

    char* ws = (char*)d_ws;
    float*          pqp     = (float*)ws;                       // 256 KB
    unsigned short* wsplit  = (unsigned short*)(ws + 262144);   // 256 KB
    unsigned short* CWt     = (unsigned short*)(ws + 524288);   // 8 KB
    float*          energy  = (float*)(ws + 532480);            // 512 KB
    float*          partial = (float*)(ws + 1056768);           // 1 MB

    prep_kernel<<<dim3(4 * B + DM + 32), 128, 0, stream>>>(query, Wq, Wmem, conv_k, Wloc, pqp, wsplit, CWt);
    energy_mfma<<<dim3(B * (T / 128)), 256, 0, stream>>>(memory, state, pqp, wsplit, CWt, v_w, v_b, energy);
    softmax_context_kernel<<<dim3(B, TSEG), 256, 0, stream>>>(energy, state, memory, alignments, new_state, partial);
    context_reduce_kernel<<<dim3(B), 256, 0, stream>>>(partial, context);
}